// Round 3
// baseline (241.063 us; speedup 1.0000x reference)
//
#include <hip/hip_runtime.h>
#include <hip/hip_bf16.h>

#define B 8
#define C 256
#define H 96
#define W 128
#define R 4
#define DD 9          // 2R+1
#define TH 2          // rows per block
#define TC 8          // channels staged per LDS chunk
#define NTHREADS 576  // 32 w-threads * TH rows * 9 di-groups

// LDS tile: TC channels x (TH + 2R) rows x (W + 2R) cols, col 0 <-> global w = -4
// 8 * 10 * 136 * 4B = 43520 B
__global__ __launch_bounds__(NTHREADS)
void corr_kernel(const float* __restrict__ x1, const float* __restrict__ x2,
                 float* __restrict__ out) {
    __shared__ float x2s[TC][TH + 2 * R][W + 2 * R];

    const int tid = threadIdx.x;
    const int tw  = tid & 31;          // 32 w-threads, 4 pixels each
    const int ty  = (tid >> 5) & 1;    // row within tile
    const int g   = tid >> 6;          // di group 0..8

    const int bid = blockIdx.x;
    const int b   = bid / (H / TH);
    const int h0  = (bid % (H / TH)) * TH;
    const int h   = h0 + ty;
    const int w4  = tw * 4;

    float4 acc[DD];
#pragma unroll
    for (int dj = 0; dj < DD; ++dj) acc[dj] = make_float4(0.f, 0.f, 0.f, 0.f);

    const int NROW = TH + 2 * R;       // 10
    const int NCOL4 = (W + 2 * R) / 4; // 34
    const int NELEM4 = TC * NROW * NCOL4; // 2720 float4s per chunk

    for (int cc = 0; cc < C; cc += TC) {
        __syncthreads();
        // ---- stage x2 chunk (with halo, zero-padded) ----
        for (int idx = tid; idx < NELEM4; idx += NTHREADS) {
            int c    = idx / (NROW * NCOL4);
            int rem  = idx - c * (NROW * NCOL4);
            int row  = rem / NCOL4;
            int col4 = rem - row * NCOL4;
            int gh   = h0 - R + row;
            float4 v = make_float4(0.f, 0.f, 0.f, 0.f);
            if (gh >= 0 && gh < H && col4 >= 1 && col4 <= 32) {
                v = *(const float4*)(x2 + (((size_t)(b * C + cc + c) * H + gh) * W
                                           + (col4 * 4 - R)));
            }
            *(float4*)(&x2s[c][row][col4 * 4]) = v;
        }
        __syncthreads();

        // ---- compute on the chunk ----
#pragma unroll
        for (int c = 0; c < TC; ++c) {
            const float4 a = *(const float4*)(x1 + (((size_t)(b * C + cc + c) * H + h) * W + w4));
            const float* wrow = &x2s[c][ty + g][w4];
            const float4 w0 = *(const float4*)(wrow);
            const float4 w1 = *(const float4*)(wrow + 4);
            const float4 w2 = *(const float4*)(wrow + 8);
            const float win[12] = {w0.x, w0.y, w0.z, w0.w,
                                   w1.x, w1.y, w1.z, w1.w,
                                   w2.x, w2.y, w2.z, w2.w};
#pragma unroll
            for (int dj = 0; dj < DD; ++dj) {
                acc[dj].x += a.x * win[dj + 0];
                acc[dj].y += a.y * win[dj + 1];
                acc[dj].z += a.z * win[dj + 2];
                acc[dj].w += a.w * win[dj + 3];
            }
        }
    }

    // ---- epilogue: scale by 1/C, coalesced float4 stores ----
    const float scale = 1.0f / (float)C;
#pragma unroll
    for (int dj = 0; dj < DD; ++dj) {
        float4 v;
        v.x = acc[dj].x * scale;
        v.y = acc[dj].y * scale;
        v.z = acc[dj].z * scale;
        v.w = acc[dj].w * scale;
        const int dd = g * DD + dj;
        *(float4*)(out + (((size_t)(b * 81 + dd) * H + h) * W + w4)) = v;
    }
}

extern "C" void kernel_launch(void* const* d_in, const int* in_sizes, int n_in,
                              void* d_out, int out_size, void* d_ws, size_t ws_size,
                              hipStream_t stream) {
    const float* x1 = (const float*)d_in[0];
    const float* x2 = (const float*)d_in[1];
    float* out = (float*)d_out;
    const int nblocks = B * (H / TH); // 384
    corr_kernel<<<nblocks, NTHREADS, 0, stream>>>(x1, x2, out);
}

// Round 6
// 153.637 us; speedup vs baseline: 1.5690x; 1.5690x over previous
//
#include <hip/hip_runtime.h>

#define Bb 8
#define Cc 256
#define Hh 96
#define Ww 128
#define CH_STRIDE (Hh * Ww)   // 12288 floats per channel plane

// 36 FMAs on one channel: acc[dj].{x,y,z,w} += a.{x,y,z,w} * win[dj + {0,1,2,3}]
#define FMA36(a, f0, f1, f2)                                        \
  do {                                                              \
    const float wn[12] = {f0.x, f0.y, f0.z, f0.w,                   \
                          f1.x, f1.y, f1.z, f1.w,                   \
                          f2.x, f2.y, f2.z, f2.w};                  \
    _Pragma("unroll")                                               \
    for (int dj = 0; dj < 9; ++dj) {                                \
      acc[dj].x += a.x * wn[dj + 0];                                \
      acc[dj].y += a.y * wn[dj + 1];                                \
      acc[dj].z += a.z * wn[dj + 2];                                \
      acc[dj].w += a.w * wn[dj + 3];                                \
    }                                                               \
  } while (0)

__global__ __launch_bounds__(256)
void corr_kernel(const float* __restrict__ x1, const float* __restrict__ x2,
                 float* __restrict__ out) {
  const int tid   = threadIdx.x;
  const int wid   = (blockIdx.x * 256 + tid) >> 6;  // 0..3455, wave-uniform
  const int lane  = tid & 63;
  const int tw    = lane & 31;   // 32 w-threads, 4 px each
  const int ty    = lane >> 5;   // row within strip
  const int g     = wid % 9;     // di
  const int strip = wid / 9;     // 0..383
  const int hs    = strip % 48;
  const int b     = strip / 48;
  const int h     = hs * 2 + ty;
  const int w4    = tw * 4;

  // x2 row for this di; clamp address, zero result via scale if OOB
  const int  hx2    = h + g - 4;
  const bool row_ok = (hx2 >= 0) && (hx2 < Hh);
  const int  hc     = row_ok ? hx2 : 0;
  // column-pad masks: f0 covers cols [w4-4,w4), f2 covers [w4+4,w4+8)
  const bool ok_f0 = (tw != 0);    // w4==0  -> cols -4..-1  are pad zeros
  const bool ok_f2 = (tw != 31);   // w4==124-> cols 128..131 are pad zeros

  const float* p1base = x1 + (((size_t)(b * Cc) * Hh + h)  * Ww + w4);
  const float* p2base = x2 + (((size_t)(b * Cc) * Hh + hc) * Ww + w4);

  float4 acc[9];
#pragma unroll
  for (int j = 0; j < 9; ++j) acc[j] = make_float4(0.f, 0.f, 0.f, 0.f);

  // ---- 1-deep ping-pong pipeline over channels ----
  float4 aA  = *(const float4*)(p1base);
  float4 f1A = *(const float4*)(p2base);
  float4 f2A = *(const float4*)(p2base + 4);
  float4 f0A = make_float4(0.f, 0.f, 0.f, 0.f);
  if (ok_f0) f0A = *(const float4*)(p2base - 4);
  if (!ok_f2) f2A = make_float4(0.f, 0.f, 0.f, 0.f);

  for (int c = 0; c < Cc; c += 2) {
    // prefetch channel c+1 into set B
    {
      const float* q1 = p1base + (size_t)(c + 1) * CH_STRIDE;
      const float* q2 = p2base + (size_t)(c + 1) * CH_STRIDE;
      float4 aB  = *(const float4*)(q1);
      float4 f1B = *(const float4*)(q2);
      float4 f2B = make_float4(0.f, 0.f, 0.f, 0.f);
      float4 f0B = make_float4(0.f, 0.f, 0.f, 0.f);
      if (ok_f2) f2B = *(const float4*)(q2 + 4);
      if (ok_f0) f0B = *(const float4*)(q2 - 4);

      FMA36(aA, f0A, f1A, f2A);

      // prefetch channel c+2 into set A ((c+2)&255 wraps to 0 on last iter; unused)
      const int c2 = (c + 2) & (Cc - 1);
      const float* r1 = p1base + (size_t)c2 * CH_STRIDE;
      const float* r2 = p2base + (size_t)c2 * CH_STRIDE;
      aA  = *(const float4*)(r1);
      f1A = *(const float4*)(r2);
      f2A = make_float4(0.f, 0.f, 0.f, 0.f);
      f0A = make_float4(0.f, 0.f, 0.f, 0.f);
      if (ok_f2) f2A = *(const float4*)(r2 + 4);
      if (ok_f0) f0A = *(const float4*)(r2 - 4);

      FMA36(aB, f0B, f1B, f2B);
    }
  }

  // ---- epilogue: scale (0 if row OOB -> whole di-plane is pad zeros) ----
  const float scale = row_ok ? (1.0f / (float)Cc) : 0.0f;
  float* po = out + (((size_t)(b * 81 + g * 9) * Hh + h) * Ww + w4);
#pragma unroll
  for (int dj = 0; dj < 9; ++dj) {
    float4 v = make_float4(acc[dj].x * scale, acc[dj].y * scale,
                           acc[dj].z * scale, acc[dj].w * scale);
    *(float4*)(po + (size_t)dj * CH_STRIDE) = v;
  }
}

extern "C" void kernel_launch(void* const* d_in, const int* in_sizes, int n_in,
                              void* d_out, int out_size, void* d_ws, size_t ws_size,
                              hipStream_t stream) {
  const float* x1 = (const float*)d_in[0];
  const float* x2 = (const float*)d_in[1];
  float* out = (float*)d_out;
  // total work-threads: 8 b * 48 strips * 9 di * 64 lanes = 221184 = 864 * 256
  corr_kernel<<<864, 256, 0, stream>>>(x1, x2, out);
}